// Round 6
// baseline (458.464 us; speedup 1.0000x reference)
//
#include <hip/hip_runtime.h>
#include <hip/hip_bf16.h>

#define LF 64
#define NBAGS 5
#define BROWS 2048
#define OUTC 320
#define KC 2048
#define MT_BLOCK 128               // 4 waves x 32 rows
#define NMT (BROWS / MT_BLOCK)     // 16
#define NCHUNKS 90                 // bags 1..4: 30 + 1 + 49 + 10

#define WS_HEAD 65536              // sums (40960 B used) + zero page
#define ZP_OFF 49152               // 4 KB zero page inside WS_HEAD
#define WP_BYTES 23068672ull       // 2816 tiles * 8192 B
#define PART_OFF (WS_HEAD + WP_BYTES)
#define PART_BYTES ((size_t)NCHUNKS * BROWS * LF * 4)

typedef __attribute__((ext_vector_type(8))) short short8;
typedef __attribute__((ext_vector_type(4))) float f32x4;

typedef const __attribute__((address_space(1))) void gas_t;
typedef __attribute__((address_space(3))) void las_t;

struct BagArgs {
    const int*   A[NBAGS];
    const float* W[NBAGS];
    int K[NBAGS];
    int cstart[NBAGS + 1];   // KC-chunk prefix, bags 1..4
    int tstart[NBAGS + 1];   // 64-k tile prefix, all bags
};

__device__ __forceinline__ unsigned short f2bf(float f) {
    unsigned u = __float_as_uint(f);
    u += 0x7FFFu + ((u >> 16) & 1u);   // round-to-nearest-even
    return (unsigned short)(u >> 16);
}

// Pack W (f32 [K][64]) -> bf16 tiles of 64 k (8 KB), permuted so the B
// fragment matches A where lane (fr,kg) holds k = kg*16+[0..15] contiguous.
// k -> block = ((k>>3)&1)*4 + (k>>4);  short idx = (block*64 + c)*8 + (k&7).
// Zero-filled past K.  [validated R5]
__global__ __launch_bounds__(256) void pack_w(BagArgs args,
                                              unsigned short* __restrict__ Wp) {
    __shared__ unsigned short ls[4][4096];
    const int wv = threadIdx.x >> 6;
    const int c  = threadIdx.x & 63;
    const int gtile = blockIdx.x * 4 + wv;

    int bag = 0;
#pragma unroll
    for (int b = 1; b < NBAGS; ++b)
        if (gtile >= args.tstart[b]) bag = b;
    const int lt = gtile - args.tstart[bag];
    const float* __restrict__ W = args.W[bag];
    const int K = args.K[bag];

    unsigned short* L = ls[wv];
#pragma unroll 8
    for (int k = 0; k < 64; ++k) {
        const int gk = lt * 64 + k;
        float v = (gk < K) ? W[(size_t)gk * LF + c] : 0.f;
        const int block = ((k >> 3) & 1) * 4 + (k >> 4);
        L[(block * LF + c) * 8 + (k & 7)] = f2bf(v);
    }
    __syncthreads();
    unsigned short* dst = Wp + ((size_t)gtile << 12);
#pragma unroll
    for (int j = 0; j < 8; ++j)
        *(short8*)(dst + c * 8 + j * 512) = *(const short8*)(L + c * 8 + j * 512);
}

// Streaming GEMM: all A/B bytes via global_load_lds (zero VGPR in-flight
// cost), double-buffered LDS, counted vmcnt + raw s_barrier (T3/T4 recipe).
__global__ __launch_bounds__(256) void bag_gemm(BagArgs args,
                                                const unsigned short* __restrict__ Wp,
                                                const int* __restrict__ zp,
                                                float* __restrict__ part,
                                                int* __restrict__ sums)
{
    __shared__ char lds[2][40960];     // per buf: A 32 KB @0, B 8 KB @32768

    const int tid  = threadIdx.x;
    const int wave = tid >> 6;
    const int lane = tid & 63;
    const int fr   = lane & 15;
    const int kg   = lane >> 4;

    const int g  = blockIdx.x >> 4;    // global chunk (bags 1..4)
    const int mt = blockIdx.x & 15;    // m-tile (128 rows)

    int bag = 1;
#pragma unroll
    for (int b = 2; b < NBAGS; ++b)
        if (g >= args.cstart[b]) bag = b;
    const int chunk  = g - args.cstart[bag];
    const int K      = args.K[bag];
    const int kc0    = chunk * KC;
    const int kend   = min(kc0 + KC, K);
    const int nsuper = (kend - kc0 + 63) >> 6;
    const int tile0  = args.tstart[bag] + chunk * (KC / 64);

    const int row0 = mt * MT_BLOCK + wave * 32;
    const int* __restrict__ Abase = args.A[bag];

    // DMA one 64-k superstep: A 8 KB/wave (8 instrs) + B 2 KB/wave (2 instrs).
    // LDS A image: wave*8192 + (j*2+rs)*1024 + lane*16 holds
    //   row = row0+rs*16+fr, ints col = kc0+ss*64+kg*16+j*4 .. +3.
    auto stage = [&](int ss, int bufi) {
        char* dA = &lds[bufi][0] + wave * 8192;
#pragma unroll
        for (int i = 0; i < 8; ++i) {
            const int rs = i & 1, j = i >> 1;
            const int col = kc0 + ss * 64 + kg * 16 + j * 4;
            const int row = row0 + rs * 16 + fr;
            const int* src = Abase + (size_t)row * K + col;
            if (col >= kend) src = zp;              // tail: stream zeros
            __builtin_amdgcn_global_load_lds((gas_t*)src, (las_t*)(dA + i * 1024),
                                             16, 0, 0);
        }
        const char* sB = (const char*)Wp + ((size_t)(tile0 + ss) << 13)
                         + wave * 2048 + lane * 16;
        char* dB = &lds[bufi][32768] + wave * 2048;
        __builtin_amdgcn_global_load_lds((gas_t*)sB, (las_t*)dB, 16, 0, 0);
        __builtin_amdgcn_global_load_lds((gas_t*)(sB + 1024), (las_t*)(dB + 1024),
                                         16, 0, 0);
    };

    f32x4 acc0[4], acc1[4];
#pragma unroll
    for (int i = 0; i < 4; ++i) {
        acc0[i] = (f32x4){0.f, 0.f, 0.f, 0.f};
        acc1[i] = (f32x4){0.f, 0.f, 0.f, 0.f};
    }
    int ps0 = 0, ps1 = 0;

    stage(0, 0);
    if (nsuper > 1) stage(1, 1);

    for (int ss = 0; ss < nsuper; ++ss) {
        const int cur = ss & 1;
        // wait for stage(ss); leave stage(ss+1)'s 10 DMA in flight
        if (ss + 1 < nsuper) asm volatile("s_waitcnt vmcnt(10)" ::: "memory");
        else                 asm volatile("s_waitcnt vmcnt(0)"  ::: "memory");
        __builtin_amdgcn_sched_barrier(0);
        __builtin_amdgcn_s_barrier();

        const char* Ab = &lds[cur][0]     + wave * 8192 + kg * 256 + fr * 16;
        const char* Bb = &lds[cur][32768] + kg * 1024 + fr * 16;

        short8 fa[2][2];
#pragma unroll
        for (int m = 0; m < 2; ++m)
#pragma unroll
            for (int rs = 0; rs < 2; ++rs) {
                int4 lo = *(const int4*)(Ab + (size_t)(4 * m + rs) * 1024);
                int4 hi = *(const int4*)(Ab + (size_t)(4 * m + 2 + rs) * 1024);
                const int s = lo.x + lo.y + lo.z + lo.w + hi.x + hi.y + hi.z + hi.w;
                if (rs == 0) ps0 += s; else ps1 += s;
                // ints are exactly {0,1}: (x|y<<16)*0x3F80 = bf16(x)|bf16(y)<<16
                const unsigned q0 = (unsigned)(lo.x | (lo.y << 16)) * 0x3F80u;
                const unsigned q1 = (unsigned)(lo.z | (lo.w << 16)) * 0x3F80u;
                const unsigned q2 = (unsigned)(hi.x | (hi.y << 16)) * 0x3F80u;
                const unsigned q3 = (unsigned)(hi.z | (hi.w << 16)) * 0x3F80u;
                int4 u = make_int4((int)q0, (int)q1, (int)q2, (int)q3);
                fa[rs][m] = *(short8*)&u;
            }
#pragma unroll
        for (int m = 0; m < 2; ++m)
#pragma unroll
            for (int ni = 0; ni < 4; ++ni) {
                const short8 y = *(const short8*)(Bb + m * 4096 + ni * 256);
                acc0[ni] = __builtin_amdgcn_mfma_f32_16x16x32_bf16(fa[0][m], y, acc0[ni], 0, 0, 0);
                acc1[ni] = __builtin_amdgcn_mfma_f32_16x16x32_bf16(fa[1][m], y, acc1[ni], 0, 0, 0);
            }

        __builtin_amdgcn_s_barrier();          // all waves done reading buf[cur]
        if (ss + 2 < nsuper) stage(ss + 2, cur);
    }

    // row popcounts: fold kg slices (lanes fr, fr+16, fr+32, fr+48)
    ps0 += __shfl_xor(ps0, 16);
    ps0 += __shfl_xor(ps0, 32);
    ps1 += __shfl_xor(ps1, 16);
    ps1 += __shfl_xor(ps1, 32);
    if (kg == 0) {
        atomicAdd(&sums[bag * BROWS + row0 + fr], ps0);
        atomicAdd(&sums[bag * BROWS + row0 + 16 + fr], ps1);
    }

    // C/D: col = lane&15 (=fr), row = kg*4 + reg   [validated R1-R5]
    float* dst = part + ((size_t)g * BROWS + row0 + kg * 4) * LF + fr;
#pragma unroll
    for (int ni = 0; ni < 4; ++ni)
#pragma unroll
        for (int r = 0; r < 4; ++r) {
            dst[(size_t)(r) * LF + ni * 16]      = acc0[ni][r];
            dst[(size_t)(16 + r) * LF + ni * 16] = acc1[ni][r];
        }
}

// Sum split-K partials, normalize (incl. faithful "decades divided twice"
// bug), and compute the tiny K=12 decades bag directly in f32.
__global__ __launch_bounds__(256) void reduce_norm(BagArgs args,
                                                   const float* __restrict__ part,
                                                   float* __restrict__ out,
                                                   const int* __restrict__ sums)
{
    const int idx = blockIdx.x * 256 + threadIdx.x;
    if (idx >= BROWS * OUTC) return;
    const int row = idx / OUTC;
    const int c   = idx - row * OUTC;
    const int bag = c >> 6;
    const int col = c & 63;

    float v;
    if (bag == 0) {
        const int*   A0 = args.A[0];
        const float* W0 = args.W[0];
        float a = 0.f; int s = 0;
#pragma unroll
        for (int k = 0; k < 12; ++k) {
            const int x = A0[row * 12 + k];
            s += x;
            if (x) a += W0[k * LF + col];
        }
        if (s) a /= (float)s;
        const int sm = sums[1 * BROWS + row];   // ref bug: also divide by movie sum
        if (sm) a /= (float)sm;
        v = a;
    } else {
        float a = 0.f;
        for (int gg = args.cstart[bag]; gg < args.cstart[bag + 1]; ++gg)
            a += part[((size_t)gg * BROWS + row) * LF + col];
        v = a;
        if (bag >= 2) {
            const int s = sums[bag * BROWS + row];
            if (s) v /= (float)s;
        }
        // bag 1 (movies): never normalized (faithful to reference bug)
    }
    out[idx] = v;
}

// Correctness-only fallback (never used when ws is large): one thread per
// output element, direct f32 accumulation.
__global__ void naive_bag(BagArgs args, float* __restrict__ out) {
    const int row = blockIdx.x;
    const int c   = threadIdx.x;
    if (c >= OUTC) return;
    const int bag = c >> 6;
    const int col = c & 63;
    const int K = args.K[bag];
    const int* A = args.A[bag] + (size_t)row * K;
    const float* W = args.W[bag];
    float a = 0.f; int s = 0;
    for (int k = 0; k < K; ++k) {
        const int x = A[k];
        s += x;
        if (x) a += W[(size_t)k * LF + col];
    }
    if (bag != 1 && s) a /= (float)s;
    if (bag == 0) {
        const int* A1 = args.A[1] + (size_t)row * args.K[1];
        int sm = 0;
        for (int k = 0; k < args.K[1]; ++k) sm += A1[k];
        if (sm) a /= (float)sm;
    }
    out[(size_t)row * OUTC + c] = a;
}

extern "C" void kernel_launch(void* const* d_in, const int* in_sizes, int n_in,
                              void* d_out, int out_size, void* d_ws, size_t ws_size,
                              hipStream_t stream) {
    float* out = (float*)d_out;
    int* sums = (int*)d_ws;
    const int* zp = (const int*)((const char*)d_ws + ZP_OFF);
    unsigned short* Wp = (unsigned short*)((char*)d_ws + WS_HEAD);
    float* part = (float*)((char*)d_ws + PART_OFF);

    BagArgs args;
    const int Ks[NBAGS] = {12, 60000, 32, 100000, 20000};
    int tcum = 0;
    for (int b = 0; b < NBAGS; ++b) {
        args.A[b] = (const int*)d_in[b];
        args.W[b] = (const float*)d_in[5 + b];
        args.K[b] = Ks[b];
        args.tstart[b] = tcum;
        tcum += (Ks[b] + 63) / 64;          // -> 2816
    }
    args.tstart[NBAGS] = tcum;
    args.cstart[0] = 0;
    int ccum = 0;
    for (int b = 1; b < NBAGS; ++b) {
        args.cstart[b] = ccum;
        ccum += (Ks[b] + KC - 1) / KC;      // 30 + 1 + 49 + 10 = 90
    }
    args.cstart[NBAGS] = ccum;

    const bool ok = ws_size >= PART_OFF + PART_BYTES;
    if (!ok) {
        naive_bag<<<BROWS, OUTC, 0, stream>>>(args, out);
        return;
    }

    hipMemsetAsync(d_ws, 0, WS_HEAD, stream);   // sums + zero page

    pack_w<<<tcum / 4, 256, 0, stream>>>(args, Wp);
    bag_gemm<<<NCHUNKS * NMT, 256, 0, stream>>>(args, Wp, zp, part, sums);
    reduce_norm<<<(BROWS * OUTC + 255) / 256, 256, 0, stream>>>(args, part, out, sums);
}